// Round 1
// baseline (3459.355 us; speedup 1.0000x reference)
//
#include <hip/hip_runtime.h>

#define NN 100000
#define NE 600000
constexpr int FIN = 128;

// ---------------- utility kernels ----------------

__global__ __launch_bounds__(256) void k_zero(float4* p, int n4) {
  int i = blockIdx.x * blockDim.x + threadIdx.x;
  int st = gridDim.x * blockDim.x;
  for (; i < n4; i += st) p[i] = make_float4(0.f, 0.f, 0.f, 0.f);
}

__global__ __launch_bounds__(256) void k_count(const int* __restrict__ dst,
                                               float* __restrict__ cnt) {
  int e = blockIdx.x * blockDim.x + threadIdx.x;
  if (e < NE) {
    int d = dst[e];
    if ((unsigned)d < NN) atomicAdd(&cnt[d], 1.0f);
  }
}

__global__ __launch_bounds__(256) void k_invert(float* __restrict__ c) {
  int i = blockIdx.x * blockDim.x + threadIdx.x;
  if (i < NN) c[i] = 1.0f / fmaxf(c[i], 1.0f);
}

// scatter-add: one thread = one float4 of one edge (32 threads/edge)
__global__ __launch_bounds__(256) void k_scatter(const int* __restrict__ src,
                                                 const int* __restrict__ dst,
                                                 const float* __restrict__ h,
                                                 float* __restrict__ msum) {
  int t = blockIdx.x * blockDim.x + threadIdx.x;
  int e = t >> 5;
  int f4 = t & 31;
  if (e >= NE) return;
  int s = src[e];
  int d = dst[e];
  if ((unsigned)s >= NN || (unsigned)d >= NN) return;
  float4 v = *reinterpret_cast<const float4*>(h + (size_t)s * FIN + f4 * 4);
  float* o = msum + (size_t)d * FIN + f4 * 4;
  atomicAdd(o + 0, v.x);
  atomicAdd(o + 1, v.y);
  atomicAdd(o + 2, v.z);
  atomicAdd(o + 3, v.w);
}

// build WT[k][j] : k in [0,256), j in [0,FOUT);  k<128 -> Wl[j][k], else Wr[j][k-128]
template <int FOUT>
__global__ __launch_bounds__(256) void k_transpose(const float* __restrict__ Wl,
                                                   const float* __restrict__ Wr,
                                                   float* __restrict__ wt) {
  int idx = blockIdx.x * blockDim.x + threadIdx.x;
  if (idx >= 256 * FOUT) return;
  int k = idx / FOUT;
  int j = idx - k * FOUT;
  float v = (k < 128) ? Wl[j * 128 + k] : Wr[j * 128 + (k - 128)];
  wt[idx] = v;
}

// fused: out[n][j] = relu?( sum_k A[n][k]*WT[k][j] + bias[j] )
// A[n][k] = (k<128) ? msum[n][k]*inv[n] : h[n][k-128]
template <int FOUT, bool RELU>
__global__ __launch_bounds__(256) void k_gemm(const float* __restrict__ h,
                                              const float* __restrict__ msum,
                                              const float* __restrict__ inv,
                                              const float* __restrict__ wt,
                                              const float* __restrict__ bias,
                                              float* __restrict__ out) {
  constexpr int TN4 = FOUT / 64;  // float4's per thread along j (2 for 128, 1 for 64)
  __shared__ float A[64][68];     // 64 nodes x 64 k-chunk, padded (68*4B = 272B, 16B-aligned rows)
  __shared__ float B[64][FOUT];   // k-chunk x FOUT

  const int t = threadIdx.x;
  const int tx = t & 15;   // j group
  const int ty = t >> 4;   // node group
  const int n0 = blockIdx.x * 64;

  float acc[4][TN4 * 4];
#pragma unroll
  for (int i = 0; i < 4; ++i)
#pragma unroll
    for (int q = 0; q < TN4 * 4; ++q) acc[i][q] = 0.f;

  const int arow = t >> 2;          // node row this thread stages (0..63)
  const int acol = t & 3;           // base float4 col
  const int anode = n0 + arow;
  const float ainv = (anode < NN) ? inv[anode] : 0.f;

  for (int chunk = 0; chunk < 4; ++chunk) {
    const int k0 = chunk * 64;
    const bool meanp = (chunk < 2);
    const float* sb = meanp ? msum : h;
    const int kb = meanp ? k0 : (k0 - 128);
    const float sc = meanp ? ainv : 1.0f;

    // stage A tile: each thread 4x float4
#pragma unroll
    for (int i = 0; i < 4; ++i) {
      int c4 = acol + i * 4;  // 0..15
      float4 v = make_float4(0.f, 0.f, 0.f, 0.f);
      if (anode < NN)
        v = *reinterpret_cast<const float4*>(sb + (size_t)anode * FIN + kb + c4 * 4);
      v.x *= sc; v.y *= sc; v.z *= sc; v.w *= sc;
      *reinterpret_cast<float4*>(&A[arow][c4 * 4]) = v;
    }
    // stage B tile: 64 x FOUT floats, coalesced from WT
#pragma unroll
    for (int i = 0; i < FOUT / 16; ++i) {
      int idx = t + i * 256;            // float4 index over 64*FOUT/4
      int kk = idx / (FOUT / 4);
      int j4 = idx - kk * (FOUT / 4);
      *reinterpret_cast<float4*>(&B[kk][j4 * 4]) =
          *reinterpret_cast<const float4*>(wt + (size_t)(k0 + kk) * FOUT + j4 * 4);
    }
    __syncthreads();

#pragma unroll
    for (int kk = 0; kk < 64; ++kk) {
      float a[4];
#pragma unroll
      for (int i = 0; i < 4; ++i) a[i] = A[ty * 4 + i][kk];
      float b[TN4 * 4];
#pragma unroll
      for (int q = 0; q < TN4; ++q)
        *reinterpret_cast<float4*>(&b[q * 4]) =
            *reinterpret_cast<const float4*>(&B[kk][(tx * TN4 + q) * 4]);
#pragma unroll
      for (int i = 0; i < 4; ++i)
#pragma unroll
        for (int q = 0; q < TN4 * 4; ++q) acc[i][q] = fmaf(a[i], b[q], acc[i][q]);
    }
    __syncthreads();
  }

  // epilogue: bias (+relu) + store
  float bres[TN4 * 4];
#pragma unroll
  for (int q = 0; q < TN4; ++q)
    *reinterpret_cast<float4*>(&bres[q * 4]) =
        *reinterpret_cast<const float4*>(bias + (tx * TN4 + q) * 4);
#pragma unroll
  for (int i = 0; i < 4; ++i) {
    int n = n0 + ty * 4 + i;
    if (n < NN) {
#pragma unroll
      for (int q = 0; q < TN4; ++q) {
        float4 v;
        v.x = acc[i][q * 4 + 0] + bres[q * 4 + 0];
        v.y = acc[i][q * 4 + 1] + bres[q * 4 + 1];
        v.z = acc[i][q * 4 + 2] + bres[q * 4 + 2];
        v.w = acc[i][q * 4 + 3] + bres[q * 4 + 3];
        if (RELU) {
          v.x = fmaxf(v.x, 0.f); v.y = fmaxf(v.y, 0.f);
          v.z = fmaxf(v.z, 0.f); v.w = fmaxf(v.w, 0.f);
        }
        *reinterpret_cast<float4*>(out + (size_t)n * FOUT + (tx * TN4 + q) * 4) = v;
      }
    }
  }
}

// ---------------- launch ----------------

extern "C" void kernel_launch(void* const* d_in, const int* in_sizes, int n_in,
                              void* d_out, int out_size, void* d_ws, size_t ws_size,
                              hipStream_t stream) {
  const float* x   = (const float*)d_in[0];
  const int*   ei  = (const int*)d_in[1];
  const float* Wl0 = (const float*)d_in[2];
  const float* bl0 = (const float*)d_in[3];
  const float* Wr0 = (const float*)d_in[4];
  const float* Wl1 = (const float*)d_in[5];
  const float* bl1 = (const float*)d_in[6];
  const float* Wr1 = (const float*)d_in[7];
  const float* Wl2 = (const float*)d_in[8];
  const float* bl2 = (const float*)d_in[9];
  const float* Wr2 = (const float*)d_in[10];
  float* out = (float*)d_out;

  char* ws = (char*)d_ws;
  size_t off = 0;
  float* inv  = (float*)(ws + off); off += (((size_t)NN * 4) + 511) / 512 * 512;
  float* msum = (float*)(ws + off); off += (size_t)NN * FIN * 4;
  float* h1   = (float*)(ws + off); off += (size_t)NN * FIN * 4;
  float* h2   = (float*)(ws + off); off += (size_t)NN * FIN * 4;
  float* wt   = (float*)(ws + off); off += 256 * 128 * 4;

  const int* srcp = ei;
  const int* dstp = ei + NE;

  const int scatter_blocks = (NE * 32) / 256;  // 75000
  const int gemm_blocks = (NN + 63) / 64;      // 1563

  // degrees (graph shared across layers)
  k_zero<<<128, 256, 0, stream>>>((float4*)inv, NN / 4);
  k_count<<<(NE + 255) / 256, 256, 0, stream>>>(dstp, inv);
  k_invert<<<(NN + 255) / 256, 256, 0, stream>>>(inv);

  // layer 0: x -> h1 (relu)
  k_zero<<<2048, 256, 0, stream>>>((float4*)msum, NN * FIN / 4);
  k_scatter<<<scatter_blocks, 256, 0, stream>>>(srcp, dstp, x, msum);
  k_transpose<128><<<(256 * 128) / 256, 256, 0, stream>>>(Wl0, Wr0, wt);
  k_gemm<128, true><<<gemm_blocks, 256, 0, stream>>>(x, msum, inv, wt, bl0, h1);

  // layer 1: h1 -> h2 (relu)
  k_zero<<<2048, 256, 0, stream>>>((float4*)msum, NN * FIN / 4);
  k_scatter<<<scatter_blocks, 256, 0, stream>>>(srcp, dstp, h1, msum);
  k_transpose<128><<<(256 * 128) / 256, 256, 0, stream>>>(Wl1, Wr1, wt);
  k_gemm<128, true><<<gemm_blocks, 256, 0, stream>>>(h1, msum, inv, wt, bl1, h2);

  // layer 2: h2 -> out (no relu)
  k_zero<<<2048, 256, 0, stream>>>((float4*)msum, NN * FIN / 4);
  k_scatter<<<scatter_blocks, 256, 0, stream>>>(srcp, dstp, h2, msum);
  k_transpose<64><<<(256 * 64) / 256, 256, 0, stream>>>(Wl2, Wr2, wt);
  k_gemm<64, false><<<gemm_blocks, 256, 0, stream>>>(h2, msum, inv, wt, bl2, out);
}

// Round 2
// 571.240 us; speedup vs baseline: 6.0559x; 6.0559x over previous
//
#include <hip/hip_runtime.h>

#define NN 100000
#define NE 600000
constexpr int FIN = 128;
constexpr int SCAN_BLOCKS = (NN + 255) / 256;  // 391

// ---------------- utility kernels ----------------

__global__ __launch_bounds__(256) void k_zero(float4* p, int n4) {
  int i = blockIdx.x * blockDim.x + threadIdx.x;
  int st = gridDim.x * blockDim.x;
  for (; i < n4; i += st) p[i] = make_float4(0.f, 0.f, 0.f, 0.f);
}

__global__ __launch_bounds__(256) void k_count(const int* __restrict__ dst,
                                               int* __restrict__ deg) {
  int e = blockIdx.x * blockDim.x + threadIdx.x;
  if (e < NE) {
    int d = dst[e];
    if ((unsigned)d < NN) atomicAdd(&deg[d], 1);
  }
}

__global__ __launch_bounds__(256) void k_invdeg(const int* __restrict__ deg,
                                                float* __restrict__ inv) {
  int i = blockIdx.x * blockDim.x + threadIdx.x;
  if (i < NN) inv[i] = 1.0f / fmaxf((float)deg[i], 1.0f);
}

// ---------------- CSR build: scan + fill ----------------

// inclusive block scans of deg -> rowptr[i+1] (partial), block sums -> bsum
__global__ __launch_bounds__(256) void k_scan1(const int* __restrict__ deg,
                                               int* __restrict__ rowptr,
                                               int* __restrict__ bsum) {
  __shared__ int s[256];
  int i = blockIdx.x * 256 + threadIdx.x;
  int v = (i < NN) ? deg[i] : 0;
  s[threadIdx.x] = v;
  __syncthreads();
#pragma unroll
  for (int off = 1; off < 256; off <<= 1) {
    int t = (threadIdx.x >= off) ? s[threadIdx.x - off] : 0;
    __syncthreads();
    s[threadIdx.x] += t;
    __syncthreads();
  }
  if (i < NN) rowptr[i + 1] = s[threadIdx.x];
  if (threadIdx.x == 255) bsum[blockIdx.x] = s[255];
}

// single-block inclusive scan of bsum[0..nb)
__global__ __launch_bounds__(512) void k_scan2(int* __restrict__ bsum, int nb) {
  __shared__ int s[512];
  int v = (threadIdx.x < nb) ? bsum[threadIdx.x] : 0;
  s[threadIdx.x] = v;
  __syncthreads();
#pragma unroll
  for (int off = 1; off < 512; off <<= 1) {
    int t = (threadIdx.x >= off) ? s[threadIdx.x - off] : 0;
    __syncthreads();
    s[threadIdx.x] += t;
    __syncthreads();
  }
  if (threadIdx.x < nb) bsum[threadIdx.x] = s[threadIdx.x];
}

// add block offsets in place; set rowptr[0] = 0
__global__ __launch_bounds__(256) void k_scan3(const int* __restrict__ bsum,
                                               int* __restrict__ rowptr) {
  int i = blockIdx.x * 256 + threadIdx.x;
  if (i < NN && blockIdx.x > 0) rowptr[i + 1] += bsum[blockIdx.x - 1];
  if (i == 0) rowptr[0] = 0;
}

__global__ __launch_bounds__(256) void k_fill(const int* __restrict__ src,
                                              const int* __restrict__ dst,
                                              const int* __restrict__ rowptr,
                                              int* __restrict__ cursor,
                                              int* __restrict__ adj) {
  int e = blockIdx.x * blockDim.x + threadIdx.x;
  if (e < NE) {
    int d = dst[e];
    int s = src[e];
    if ((unsigned)d < NN && (unsigned)s < NN) {
      int pos = atomicAdd(&cursor[d], 1);
      adj[rowptr[d] + pos] = s;
    }
  }
}

// ---------------- gather-side aggregation ----------------
// one 32-lane half-wave per node; lane holds float4 (lane*4 .. +3) of the row
__global__ __launch_bounds__(256) void k_gather(const int* __restrict__ rowptr,
                                                const int* __restrict__ adj,
                                                const float* __restrict__ h,
                                                float* __restrict__ msum) {
  int node = blockIdx.x * 8 + (threadIdx.x >> 5);
  if (node >= NN) return;
  int lane = threadIdx.x & 31;
  int beg = rowptr[node];
  int end = rowptr[node + 1];
  float4 acc = make_float4(0.f, 0.f, 0.f, 0.f);
  int e = beg;
  for (; e + 1 < end; e += 2) {
    int s0 = adj[e];
    int s1 = adj[e + 1];
    float4 v0 = *reinterpret_cast<const float4*>(h + (size_t)s0 * FIN + lane * 4);
    float4 v1 = *reinterpret_cast<const float4*>(h + (size_t)s1 * FIN + lane * 4);
    acc.x += v0.x + v1.x;
    acc.y += v0.y + v1.y;
    acc.z += v0.z + v1.z;
    acc.w += v0.w + v1.w;
  }
  if (e < end) {
    int s0 = adj[e];
    float4 v0 = *reinterpret_cast<const float4*>(h + (size_t)s0 * FIN + lane * 4);
    acc.x += v0.x; acc.y += v0.y; acc.z += v0.z; acc.w += v0.w;
  }
  *reinterpret_cast<float4*>(msum + (size_t)node * FIN + lane * 4) = acc;
}

// ---------------- weight transpose ----------------
// build WT[k][j] : k in [0,256), j in [0,FOUT);  k<128 -> Wl[j][k], else Wr[j][k-128]
template <int FOUT>
__global__ __launch_bounds__(256) void k_transpose(const float* __restrict__ Wl,
                                                   const float* __restrict__ Wr,
                                                   float* __restrict__ wt) {
  int idx = blockIdx.x * blockDim.x + threadIdx.x;
  if (idx >= 256 * FOUT) return;
  int k = idx / FOUT;
  int j = idx - k * FOUT;
  float v = (k < 128) ? Wl[j * 128 + k] : Wr[j * 128 + (k - 128)];
  wt[idx] = v;
}

// ---------------- fused GEMM ----------------
// out[n][j] = relu?( sum_k A[n][k]*WT[k][j] + bias[j] )
// A[n][k] = (k<128) ? msum[n][k]*inv[n] : h[n][k-128]
template <int FOUT, bool RELU>
__global__ __launch_bounds__(256) void k_gemm(const float* __restrict__ h,
                                              const float* __restrict__ msum,
                                              const float* __restrict__ inv,
                                              const float* __restrict__ wt,
                                              const float* __restrict__ bias,
                                              float* __restrict__ out) {
  constexpr int TN4 = FOUT / 64;
  __shared__ float A[64][68];
  __shared__ float B[64][FOUT];

  const int t = threadIdx.x;
  const int tx = t & 15;
  const int ty = t >> 4;
  const int n0 = blockIdx.x * 64;

  float acc[4][TN4 * 4];
#pragma unroll
  for (int i = 0; i < 4; ++i)
#pragma unroll
    for (int q = 0; q < TN4 * 4; ++q) acc[i][q] = 0.f;

  const int arow = t >> 2;
  const int acol = t & 3;
  const int anode = n0 + arow;
  const float ainv = (anode < NN) ? inv[anode] : 0.f;

  for (int chunk = 0; chunk < 4; ++chunk) {
    const int k0 = chunk * 64;
    const bool meanp = (chunk < 2);
    const float* sb = meanp ? msum : h;
    const int kb = meanp ? k0 : (k0 - 128);
    const float sc = meanp ? ainv : 1.0f;

#pragma unroll
    for (int i = 0; i < 4; ++i) {
      int c4 = acol + i * 4;
      float4 v = make_float4(0.f, 0.f, 0.f, 0.f);
      if (anode < NN)
        v = *reinterpret_cast<const float4*>(sb + (size_t)anode * FIN + kb + c4 * 4);
      v.x *= sc; v.y *= sc; v.z *= sc; v.w *= sc;
      *reinterpret_cast<float4*>(&A[arow][c4 * 4]) = v;
    }
#pragma unroll
    for (int i = 0; i < FOUT / 16; ++i) {
      int idx = t + i * 256;
      int kk = idx / (FOUT / 4);
      int j4 = idx - kk * (FOUT / 4);
      *reinterpret_cast<float4*>(&B[kk][j4 * 4]) =
          *reinterpret_cast<const float4*>(wt + (size_t)(k0 + kk) * FOUT + j4 * 4);
    }
    __syncthreads();

#pragma unroll
    for (int kk = 0; kk < 64; ++kk) {
      float a[4];
#pragma unroll
      for (int i = 0; i < 4; ++i) a[i] = A[ty * 4 + i][kk];
      float b[TN4 * 4];
#pragma unroll
      for (int q = 0; q < TN4; ++q)
        *reinterpret_cast<float4*>(&b[q * 4]) =
            *reinterpret_cast<const float4*>(&B[kk][(tx * TN4 + q) * 4]);
#pragma unroll
      for (int i = 0; i < 4; ++i)
#pragma unroll
        for (int q = 0; q < TN4 * 4; ++q) acc[i][q] = fmaf(a[i], b[q], acc[i][q]);
    }
    __syncthreads();
  }

  float bres[TN4 * 4];
#pragma unroll
  for (int q = 0; q < TN4; ++q)
    *reinterpret_cast<float4*>(&bres[q * 4]) =
        *reinterpret_cast<const float4*>(bias + (tx * TN4 + q) * 4);
#pragma unroll
  for (int i = 0; i < 4; ++i) {
    int n = n0 + ty * 4 + i;
    if (n < NN) {
#pragma unroll
      for (int q = 0; q < TN4; ++q) {
        float4 v;
        v.x = acc[i][q * 4 + 0] + bres[q * 4 + 0];
        v.y = acc[i][q * 4 + 1] + bres[q * 4 + 1];
        v.z = acc[i][q * 4 + 2] + bres[q * 4 + 2];
        v.w = acc[i][q * 4 + 3] + bres[q * 4 + 3];
        if (RELU) {
          v.x = fmaxf(v.x, 0.f); v.y = fmaxf(v.y, 0.f);
          v.z = fmaxf(v.z, 0.f); v.w = fmaxf(v.w, 0.f);
        }
        *reinterpret_cast<float4*>(out + (size_t)n * FOUT + (tx * TN4 + q) * 4) = v;
      }
    }
  }
}

// ---------------- launch ----------------

static inline size_t align512(size_t x) { return (x + 511) & ~(size_t)511; }

extern "C" void kernel_launch(void* const* d_in, const int* in_sizes, int n_in,
                              void* d_out, int out_size, void* d_ws, size_t ws_size,
                              hipStream_t stream) {
  const float* x   = (const float*)d_in[0];
  const int*   ei  = (const int*)d_in[1];
  const float* Wl0 = (const float*)d_in[2];
  const float* bl0 = (const float*)d_in[3];
  const float* Wr0 = (const float*)d_in[4];
  const float* Wl1 = (const float*)d_in[5];
  const float* bl1 = (const float*)d_in[6];
  const float* Wr1 = (const float*)d_in[7];
  const float* Wl2 = (const float*)d_in[8];
  const float* bl2 = (const float*)d_in[9];
  const float* Wr2 = (const float*)d_in[10];
  float* out = (float*)d_out;

  char* ws = (char*)d_ws;
  size_t off = 0;
  float* inv    = (float*)(ws + off); off = align512(off + (size_t)NN * 4);
  float* msum   = (float*)(ws + off); off = align512(off + (size_t)NN * FIN * 4);
  float* h1     = (float*)(ws + off); off = align512(off + (size_t)NN * FIN * 4);
  float* h2     = (float*)(ws + off); off = align512(off + (size_t)NN * FIN * 4);
  float* wt     = (float*)(ws + off); off = align512(off + 256 * 128 * 4);
  int*   deg    = (int*)(ws + off);   off = align512(off + (size_t)NN * 4);
  int*   rowptr = (int*)(ws + off);   off = align512(off + (size_t)(NN + 1) * 4);
  int*   cursor = (int*)(ws + off);   off = align512(off + (size_t)NN * 4);
  int*   bsum   = (int*)(ws + off);   off = align512(off + (size_t)SCAN_BLOCKS * 4);
  int*   adj    = (int*)(ws + off);   off = align512(off + (size_t)NE * 4);

  const int* srcp = ei;
  const int* dstp = ei + NE;

  const int gemm_blocks = (NN + 63) / 64;       // 1563
  const int gather_blocks = (NN + 7) / 8;       // 12500

  // ---- CSR build (once; graph shared across layers) ----
  k_zero<<<128, 256, 0, stream>>>((float4*)deg, NN / 4);
  k_zero<<<128, 256, 0, stream>>>((float4*)cursor, NN / 4);
  k_count<<<(NE + 255) / 256, 256, 0, stream>>>(dstp, deg);
  k_scan1<<<SCAN_BLOCKS, 256, 0, stream>>>(deg, rowptr, bsum);
  k_scan2<<<1, 512, 0, stream>>>(bsum, SCAN_BLOCKS);
  k_scan3<<<SCAN_BLOCKS, 256, 0, stream>>>(bsum, rowptr);
  k_fill<<<(NE + 255) / 256, 256, 0, stream>>>(srcp, dstp, rowptr, cursor, adj);
  k_invdeg<<<(NN + 255) / 256, 256, 0, stream>>>(deg, inv);

  // ---- layer 0: x -> h1 (relu) ----
  k_gather<<<gather_blocks, 256, 0, stream>>>(rowptr, adj, x, msum);
  k_transpose<128><<<(256 * 128) / 256, 256, 0, stream>>>(Wl0, Wr0, wt);
  k_gemm<128, true><<<gemm_blocks, 256, 0, stream>>>(x, msum, inv, wt, bl0, h1);

  // ---- layer 1: h1 -> h2 (relu) ----
  k_gather<<<gather_blocks, 256, 0, stream>>>(rowptr, adj, h1, msum);
  k_transpose<128><<<(256 * 128) / 256, 256, 0, stream>>>(Wl1, Wr1, wt);
  k_gemm<128, true><<<gemm_blocks, 256, 0, stream>>>(h1, msum, inv, wt, bl1, h2);

  // ---- layer 2: h2 -> out (no relu) ----
  k_gather<<<gather_blocks, 256, 0, stream>>>(rowptr, adj, h2, msum);
  k_transpose<64><<<(256 * 64) / 256, 256, 0, stream>>>(Wl2, Wr2, wt);
  k_gemm<64, false><<<gemm_blocks, 256, 0, stream>>>(h2, msum, inv, wt, bl2, out);
}

// Round 3
// 376.939 us; speedup vs baseline: 9.1775x; 1.5155x over previous
//
#include <hip/hip_runtime.h>

#define NN 100000
#define NE 600000
constexpr int FIN = 128;
constexpr int SCAN_BLOCKS = (NN + 255) / 256;  // 391

typedef __attribute__((ext_vector_type(8))) short bf16x8;
typedef __attribute__((ext_vector_type(4))) float f32x4;

// ---------------- utility kernels ----------------

__global__ __launch_bounds__(256) void k_zero(float4* p, int n4) {
  int i = blockIdx.x * blockDim.x + threadIdx.x;
  int st = gridDim.x * blockDim.x;
  for (; i < n4; i += st) p[i] = make_float4(0.f, 0.f, 0.f, 0.f);
}

__global__ __launch_bounds__(256) void k_count(const int* __restrict__ dst,
                                               int* __restrict__ deg) {
  int e = blockIdx.x * blockDim.x + threadIdx.x;
  if (e < NE) {
    int d = dst[e];
    if ((unsigned)d < NN) atomicAdd(&deg[d], 1);
  }
}

__global__ __launch_bounds__(256) void k_invdeg(const int* __restrict__ deg,
                                                float* __restrict__ inv) {
  int i = blockIdx.x * blockDim.x + threadIdx.x;
  if (i < NN) inv[i] = 1.0f / fmaxf((float)deg[i], 1.0f);
}

// ---------------- CSR build: scan + fill ----------------

__global__ __launch_bounds__(256) void k_scan1(const int* __restrict__ deg,
                                               int* __restrict__ rowptr,
                                               int* __restrict__ bsum) {
  __shared__ int s[256];
  int i = blockIdx.x * 256 + threadIdx.x;
  int v = (i < NN) ? deg[i] : 0;
  s[threadIdx.x] = v;
  __syncthreads();
#pragma unroll
  for (int off = 1; off < 256; off <<= 1) {
    int t = (threadIdx.x >= off) ? s[threadIdx.x - off] : 0;
    __syncthreads();
    s[threadIdx.x] += t;
    __syncthreads();
  }
  if (i < NN) rowptr[i + 1] = s[threadIdx.x];
  if (threadIdx.x == 255) bsum[blockIdx.x] = s[255];
}

__global__ __launch_bounds__(512) void k_scan2(int* __restrict__ bsum, int nb) {
  __shared__ int s[512];
  int v = (threadIdx.x < nb) ? bsum[threadIdx.x] : 0;
  s[threadIdx.x] = v;
  __syncthreads();
#pragma unroll
  for (int off = 1; off < 512; off <<= 1) {
    int t = (threadIdx.x >= off) ? s[threadIdx.x - off] : 0;
    __syncthreads();
    s[threadIdx.x] += t;
    __syncthreads();
  }
  if (threadIdx.x < nb) bsum[threadIdx.x] = s[threadIdx.x];
}

__global__ __launch_bounds__(256) void k_scan3(const int* __restrict__ bsum,
                                               int* __restrict__ rowptr) {
  int i = blockIdx.x * 256 + threadIdx.x;
  if (i < NN && blockIdx.x > 0) rowptr[i + 1] += bsum[blockIdx.x - 1];
  if (i == 0) rowptr[0] = 0;
}

__global__ __launch_bounds__(256) void k_fill(const int* __restrict__ src,
                                              const int* __restrict__ dst,
                                              const int* __restrict__ rowptr,
                                              int* __restrict__ cursor,
                                              int* __restrict__ adj) {
  int e = blockIdx.x * blockDim.x + threadIdx.x;
  if (e < NE) {
    int d = dst[e];
    int s = src[e];
    if ((unsigned)d < NN && (unsigned)s < NN) {
      int pos = atomicAdd(&cursor[d], 1);
      adj[rowptr[d] + pos] = s;
    }
  }
}

// ---------------- gather-side aggregation ----------------
__global__ __launch_bounds__(256) void k_gather(const int* __restrict__ rowptr,
                                                const int* __restrict__ adj,
                                                const float* __restrict__ h,
                                                float* __restrict__ msum) {
  int node = blockIdx.x * 8 + (threadIdx.x >> 5);
  if (node >= NN) return;
  int lane = threadIdx.x & 31;
  int beg = rowptr[node];
  int end = rowptr[node + 1];
  float4 acc = make_float4(0.f, 0.f, 0.f, 0.f);
  int e = beg;
  for (; e + 1 < end; e += 2) {
    int s0 = adj[e];
    int s1 = adj[e + 1];
    float4 v0 = *reinterpret_cast<const float4*>(h + (size_t)s0 * FIN + lane * 4);
    float4 v1 = *reinterpret_cast<const float4*>(h + (size_t)s1 * FIN + lane * 4);
    acc.x += v0.x + v1.x;
    acc.y += v0.y + v1.y;
    acc.z += v0.z + v1.z;
    acc.w += v0.w + v1.w;
  }
  if (e < end) {
    int s0 = adj[e];
    float4 v0 = *reinterpret_cast<const float4*>(h + (size_t)s0 * FIN + lane * 4);
    acc.x += v0.x; acc.y += v0.y; acc.z += v0.z; acc.w += v0.w;
  }
  *reinterpret_cast<float4*>(msum + (size_t)node * FIN + lane * 4) = acc;
}

// ---------------- weight pre-cast: wbf[j][k], k<128 -> Wl[j][k], else Wr[j][k-128]
template <int FOUT>
__global__ __launch_bounds__(256) void k_castw(const float* __restrict__ Wl,
                                               const float* __restrict__ Wr,
                                               short* __restrict__ wbf) {
  int idx = blockIdx.x * 256 + threadIdx.x;
  if (idx >= FOUT * 256) return;
  int j = idx >> 8;
  int k = idx & 255;
  float v = (k < 128) ? Wl[j * 128 + k] : Wr[j * 128 + (k - 128)];
  unsigned u = __float_as_uint(v);
  u += 0x7FFFu + ((u >> 16) & 1u);  // RNE to bf16
  wbf[idx] = (short)(u >> 16);
}

// ---------------- MFMA GEMM (split-A bf16, fp32 accum) ----------------
// C[n][j] = sum_k A[n][k]*W[j][k] + bias[j];  A[n][k] = k<128 ? msum[n][k]*inv[n] : h[n][k-128]
// Block: 256 thr = 4 waves; wave w owns rows [b*128 + w*32, +32). No LDS, no barriers.
__device__ __forceinline__ void split8(const float* f, bf16x8& hi, bf16x8& lo) {
#pragma unroll
  for (int i = 0; i < 8; ++i) {
    unsigned u = __float_as_uint(f[i]);
    hi[i] = (short)(u >> 16);                       // truncate (lo catches residual)
    float r = f[i] - __uint_as_float(u & 0xFFFF0000u);
    lo[i] = (short)(__float_as_uint(r) >> 16);
  }
}

template <int FOUT, bool RELU>
__global__ __launch_bounds__(256) void k_gemm_mfma(
    const float* __restrict__ h, const float* __restrict__ msum,
    const float* __restrict__ inv, const short* __restrict__ wbf,
    const float* __restrict__ bias, float* __restrict__ out) {
  constexpr int NCT = FOUT / 16;
  const int lane = threadIdx.x & 63;
  const int w = threadIdx.x >> 6;
  const int l15 = lane & 15;
  const int lq = lane >> 4;
  const int n0 = blockIdx.x * 128 + w * 32;

  f32x4 acc[2][NCT];
#pragma unroll
  for (int rt = 0; rt < 2; ++rt)
#pragma unroll
    for (int c = 0; c < NCT; ++c)
#pragma unroll
      for (int q = 0; q < 4; ++q) acc[rt][c][q] = 0.f;

  const int row0 = n0 + l15;
  const int row1 = n0 + 16 + l15;
  const float inv0 = (row0 < NN) ? inv[row0] : 0.f;
  const float inv1 = (row1 < NN) ? inv[row1] : 0.f;

  for (int chunk = 0; chunk < 4; ++chunk) {
    const float* __restrict__ src = (chunk < 2) ? msum : h;
    const int kb = (chunk & 1) * 64;
    bf16x8 ah[2][2], al[2][2];
#pragma unroll
    for (int rt = 0; rt < 2; ++rt) {
      const int r = rt ? row1 : row0;
      const float s = (chunk < 2) ? (rt ? inv1 : inv0) : 1.0f;
      const bool ok = (r < NN);
      const float* p = src + (size_t)r * FIN + kb + lq * 8;
#pragma unroll
      for (int ks = 0; ks < 2; ++ks) {
        float f[8];
        if (ok) {
          float4 v0 = *reinterpret_cast<const float4*>(p + ks * 32);
          float4 v1 = *reinterpret_cast<const float4*>(p + ks * 32 + 4);
          f[0] = v0.x * s; f[1] = v0.y * s; f[2] = v0.z * s; f[3] = v0.w * s;
          f[4] = v1.x * s; f[5] = v1.y * s; f[6] = v1.z * s; f[7] = v1.w * s;
        } else {
#pragma unroll
          for (int i = 0; i < 8; ++i) f[i] = 0.f;
        }
        split8(f, ah[rt][ks], al[rt][ks]);
      }
    }
    const int kbase = chunk * 64 + lq * 8;
#pragma unroll
    for (int c = 0; c < NCT; ++c) {
      const short* bp = wbf + (size_t)(c * 16 + l15) * 256 + kbase;
#pragma unroll
      for (int ks = 0; ks < 2; ++ks) {
        bf16x8 b = *reinterpret_cast<const bf16x8*>(bp + ks * 32);
        // operands swapped: D = W_tile @ A_tile -> lane holds C[row=l15][4 consecutive cols]
        acc[0][c] = __builtin_amdgcn_mfma_f32_16x16x32_bf16(b, ah[0][ks], acc[0][c], 0, 0, 0);
        acc[0][c] = __builtin_amdgcn_mfma_f32_16x16x32_bf16(b, al[0][ks], acc[0][c], 0, 0, 0);
        acc[1][c] = __builtin_amdgcn_mfma_f32_16x16x32_bf16(b, ah[1][ks], acc[1][c], 0, 0, 0);
        acc[1][c] = __builtin_amdgcn_mfma_f32_16x16x32_bf16(b, al[1][ks], acc[1][c], 0, 0, 0);
      }
    }
  }

  // epilogue: bias (+relu), float4 coalesced stores
#pragma unroll
  for (int c = 0; c < NCT; ++c) {
    const f32x4 bb = *reinterpret_cast<const f32x4*>(bias + c * 16 + lq * 4);
#pragma unroll
    for (int rt = 0; rt < 2; ++rt) {
      const int r = rt ? row1 : row0;
      if (r < NN) {
        f32x4 v = acc[rt][c] + bb;
        if (RELU) {
#pragma unroll
          for (int q = 0; q < 4; ++q) v[q] = fmaxf(v[q], 0.f);
        }
        *reinterpret_cast<f32x4*>(out + (size_t)r * FOUT + c * 16 + lq * 4) = v;
      }
    }
  }
}

// ---------------- launch ----------------

static inline size_t align512(size_t x) { return (x + 511) & ~(size_t)511; }

extern "C" void kernel_launch(void* const* d_in, const int* in_sizes, int n_in,
                              void* d_out, int out_size, void* d_ws, size_t ws_size,
                              hipStream_t stream) {
  const float* x   = (const float*)d_in[0];
  const int*   ei  = (const int*)d_in[1];
  const float* Wl0 = (const float*)d_in[2];
  const float* bl0 = (const float*)d_in[3];
  const float* Wr0 = (const float*)d_in[4];
  const float* Wl1 = (const float*)d_in[5];
  const float* bl1 = (const float*)d_in[6];
  const float* Wr1 = (const float*)d_in[7];
  const float* Wl2 = (const float*)d_in[8];
  const float* bl2 = (const float*)d_in[9];
  const float* Wr2 = (const float*)d_in[10];
  float* out = (float*)d_out;

  char* ws = (char*)d_ws;
  size_t off = 0;
  float* inv    = (float*)(ws + off); off = align512(off + (size_t)NN * 4);
  float* msum   = (float*)(ws + off); off = align512(off + (size_t)NN * FIN * 4);
  float* h1     = (float*)(ws + off); off = align512(off + (size_t)NN * FIN * 4);
  float* h2     = (float*)(ws + off); off = align512(off + (size_t)NN * FIN * 4);
  short* wbf    = (short*)(ws + off); off = align512(off + (size_t)128 * 256 * 2);
  int*   deg    = (int*)(ws + off);   off = align512(off + (size_t)NN * 4);
  int*   rowptr = (int*)(ws + off);   off = align512(off + (size_t)(NN + 1) * 4);
  int*   cursor = (int*)(ws + off);   off = align512(off + (size_t)NN * 4);
  int*   bsum   = (int*)(ws + off);   off = align512(off + (size_t)SCAN_BLOCKS * 4);
  int*   adj    = (int*)(ws + off);   off = align512(off + (size_t)NE * 4);

  const int* srcp = ei;
  const int* dstp = ei + NE;

  const int gemm_blocks = (NN + 127) / 128;   // 782
  const int gather_blocks = (NN + 7) / 8;     // 12500

  // ---- CSR build (once; graph shared across layers) ----
  k_zero<<<128, 256, 0, stream>>>((float4*)deg, NN / 4);
  k_zero<<<128, 256, 0, stream>>>((float4*)cursor, NN / 4);
  k_count<<<(NE + 255) / 256, 256, 0, stream>>>(dstp, deg);
  k_scan1<<<SCAN_BLOCKS, 256, 0, stream>>>(deg, rowptr, bsum);
  k_scan2<<<1, 512, 0, stream>>>(bsum, SCAN_BLOCKS);
  k_scan3<<<SCAN_BLOCKS, 256, 0, stream>>>(bsum, rowptr);
  k_fill<<<(NE + 255) / 256, 256, 0, stream>>>(srcp, dstp, rowptr, cursor, adj);
  k_invdeg<<<(NN + 255) / 256, 256, 0, stream>>>(deg, inv);

  // ---- layer 0: x -> h1 (relu) ----
  k_gather<<<gather_blocks, 256, 0, stream>>>(rowptr, adj, x, msum);
  k_castw<128><<<128, 256, 0, stream>>>(Wl0, Wr0, wbf);
  k_gemm_mfma<128, true><<<gemm_blocks, 256, 0, stream>>>(x, msum, inv, wbf, bl0, h1);

  // ---- layer 1: h1 -> h2 (relu) ----
  k_gather<<<gather_blocks, 256, 0, stream>>>(rowptr, adj, h1, msum);
  k_castw<128><<<128, 256, 0, stream>>>(Wl1, Wr1, wbf);
  k_gemm_mfma<128, true><<<gemm_blocks, 256, 0, stream>>>(h1, msum, inv, wbf, bl1, h2);

  // ---- layer 2: h2 -> out (no relu) ----
  k_gather<<<gather_blocks, 256, 0, stream>>>(rowptr, adj, h2, msum);
  k_castw<64><<<64, 256, 0, stream>>>(Wl2, Wr2, wbf);
  k_gemm_mfma<64, false><<<gemm_blocks, 256, 0, stream>>>(h2, msum, inv, wbf, bl2, out);
}

// Round 4
// 322.050 us; speedup vs baseline: 10.7417x; 1.1704x over previous
//
#include <hip/hip_runtime.h>

#define NN 100000
#define NE 600000
constexpr int FIN = 128;
constexpr int SCAN_BLOCKS = (NN + 255) / 256;  // 391

typedef __attribute__((ext_vector_type(8))) short bf16x8;
typedef __attribute__((ext_vector_type(4))) float f32x4;

// ---------------- utility kernels ----------------

__global__ __launch_bounds__(256) void k_zero(float4* p, int n4) {
  int i = blockIdx.x * blockDim.x + threadIdx.x;
  int st = gridDim.x * blockDim.x;
  for (; i < n4; i += st) p[i] = make_float4(0.f, 0.f, 0.f, 0.f);
}

__global__ __launch_bounds__(256) void k_count(const int* __restrict__ dst,
                                               int* __restrict__ deg) {
  int e = blockIdx.x * blockDim.x + threadIdx.x;
  if (e < NE) {
    int d = dst[e];
    if ((unsigned)d < NN) atomicAdd(&deg[d], 1);
  }
}

__global__ __launch_bounds__(256) void k_invdeg(const int* __restrict__ deg,
                                                float* __restrict__ inv) {
  int i = blockIdx.x * blockDim.x + threadIdx.x;
  if (i < NN) inv[i] = 1.0f / fmaxf((float)deg[i], 1.0f);
}

// ---------------- CSR build: scan + fill ----------------

__global__ __launch_bounds__(256) void k_scan1(const int* __restrict__ deg,
                                               int* __restrict__ rowptr,
                                               int* __restrict__ bsum) {
  __shared__ int s[256];
  int i = blockIdx.x * 256 + threadIdx.x;
  int v = (i < NN) ? deg[i] : 0;
  s[threadIdx.x] = v;
  __syncthreads();
#pragma unroll
  for (int off = 1; off < 256; off <<= 1) {
    int t = (threadIdx.x >= off) ? s[threadIdx.x - off] : 0;
    __syncthreads();
    s[threadIdx.x] += t;
    __syncthreads();
  }
  if (i < NN) rowptr[i + 1] = s[threadIdx.x];
  if (threadIdx.x == 255) bsum[blockIdx.x] = s[255];
}

__global__ __launch_bounds__(512) void k_scan2(int* __restrict__ bsum, int nb) {
  __shared__ int s[512];
  int v = (threadIdx.x < nb) ? bsum[threadIdx.x] : 0;
  s[threadIdx.x] = v;
  __syncthreads();
#pragma unroll
  for (int off = 1; off < 512; off <<= 1) {
    int t = (threadIdx.x >= off) ? s[threadIdx.x - off] : 0;
    __syncthreads();
    s[threadIdx.x] += t;
    __syncthreads();
  }
  if (threadIdx.x < nb) bsum[threadIdx.x] = s[threadIdx.x];
}

__global__ __launch_bounds__(256) void k_scan3(const int* __restrict__ bsum,
                                               int* __restrict__ rowptr) {
  int i = blockIdx.x * 256 + threadIdx.x;
  if (i < NN && blockIdx.x > 0) rowptr[i + 1] += bsum[blockIdx.x - 1];
  if (i == 0) rowptr[0] = 0;
}

__global__ __launch_bounds__(256) void k_fill(const int* __restrict__ src,
                                              const int* __restrict__ dst,
                                              const int* __restrict__ rowptr,
                                              int* __restrict__ cursor,
                                              int* __restrict__ adj) {
  int e = blockIdx.x * blockDim.x + threadIdx.x;
  if (e < NE) {
    int d = dst[e];
    int s = src[e];
    if ((unsigned)d < NN && (unsigned)s < NN) {
      int pos = atomicAdd(&cursor[d], 1);
      adj[rowptr[d] + pos] = s;
    }
  }
}

// ---------------- weight pre-cast into per-lane packed fragment order ----
// packed element pidx = (((chunk*NCT + c)*2 + ks)*64 + lane)*8 + t
// value = bf16( W[j=c*16+(lane&15)][k=chunk*64+ks*32+(lane>>4)*8+t] ),
// W = [Wl | Wr] concatenated along k.
template <int FOUT>
__global__ __launch_bounds__(256) void k_castw(const float* __restrict__ Wl,
                                               const float* __restrict__ Wr,
                                               short* __restrict__ wpk) {
  constexpr int NCT = FOUT / 16;
  int pidx = blockIdx.x * 256 + threadIdx.x;
  if (pidx >= FOUT * 256) return;
  int t = pidx & 7;
  int lane = (pidx >> 3) & 63;
  int ks = (pidx >> 9) & 1;
  int c = (pidx >> 10) & (NCT - 1);
  int chunk = pidx >> (10 + (NCT == 8 ? 3 : 2));
  int l15 = lane & 15, lq = lane >> 4;
  int j = c * 16 + l15;
  int k = chunk * 64 + ks * 32 + lq * 8 + t;
  float v = (k < 128) ? Wl[j * 128 + k] : Wr[j * 128 + (k - 128)];
  unsigned u = __float_as_uint(v);
  u += 0x7FFFu + ((u >> 16) & 1u);  // RNE to bf16
  wpk[pidx] = (short)(u >> 16);
}

// ---------------- fused gather + MFMA GEMM ----------------
// Each wave owns 16 output rows. Phase 1: gather mean rows into wave-private
// LDS (no barriers anywhere). Phase 2: split-bf16 MFMA over K=256
// ([mean | h] concat), bias+relu epilogue.
__device__ __forceinline__ void split8(const float* f, bf16x8& hi, bf16x8& lo) {
#pragma unroll
  for (int i = 0; i < 8; ++i) {
    unsigned u = __float_as_uint(f[i]);
    hi[i] = (short)(u >> 16);  // truncate; lo catches residual
    float r = f[i] - __uint_as_float(u & 0xFFFF0000u);
    lo[i] = (short)(__float_as_uint(r) >> 16);
  }
}

template <int FOUT, bool RELU>
__global__ __launch_bounds__(256, 4) void k_fused(
    const int* __restrict__ rowptr, const int* __restrict__ adj,
    const float* __restrict__ h, const float* __restrict__ inv,
    const short* __restrict__ wpk, const float* __restrict__ bias,
    float* __restrict__ out) {
  constexpr int NCT = FOUT / 16;
  constexpr int LSTR = 132;  // +4 pad: A-frag reads land 2-way on banks (free)
  __shared__ float lds[4][16 * LSTR];
  const int lane = threadIdx.x & 63;
  const int w = threadIdx.x >> 6;
  const int l15 = lane & 15;
  const int lq = lane >> 4;
  const int half = lane >> 5;
  const int l31 = lane & 31;
  const int n0 = blockIdx.x * 64 + w * 16;
  float* myLds = lds[w];

  // ---- phase 1: gather (2 nodes per iteration, one per half-wave) ----
  for (int i = 0; i < 8; ++i) {
    int node = n0 + 2 * i + half;
    float4 acc = make_float4(0.f, 0.f, 0.f, 0.f);
    float s = 0.f;
    if (node < NN) {
      int beg = rowptr[node];
      int end = rowptr[node + 1];
      s = inv[node];
      int e = beg;
      for (; e + 1 < end; e += 2) {
        int s0 = adj[e], s1 = adj[e + 1];
        float4 v0 = *reinterpret_cast<const float4*>(h + (size_t)s0 * FIN + l31 * 4);
        float4 v1 = *reinterpret_cast<const float4*>(h + (size_t)s1 * FIN + l31 * 4);
        acc.x += v0.x + v1.x; acc.y += v0.y + v1.y;
        acc.z += v0.z + v1.z; acc.w += v0.w + v1.w;
      }
      if (e < end) {
        int s0 = adj[e];
        float4 v0 = *reinterpret_cast<const float4*>(h + (size_t)s0 * FIN + l31 * 4);
        acc.x += v0.x; acc.y += v0.y; acc.z += v0.z; acc.w += v0.w;
      }
    }
    float4 m = make_float4(acc.x * s, acc.y * s, acc.z * s, acc.w * s);
    *reinterpret_cast<float4*>(&myLds[(2 * i + half) * LSTR + l31 * 4]) = m;
  }

  // ---- phase 2: MFMA over 4 K-chunks of 64 ----
  f32x4 acc[NCT];
#pragma unroll
  for (int c = 0; c < NCT; ++c)
#pragma unroll
    for (int q = 0; q < 4; ++q) acc[c][q] = 0.f;

  const int row = n0 + l15;
  const bool ok = (row < NN);

  for (int chunk = 0; chunk < 4; ++chunk) {
    bf16x8 ah[2], al[2];
    if (chunk < 2) {
      const float* p = &myLds[l15 * LSTR + chunk * 64 + lq * 8];
#pragma unroll
      for (int ks = 0; ks < 2; ++ks) {
        float f[8];
        *reinterpret_cast<f32x4*>(&f[0]) = *reinterpret_cast<const f32x4*>(p + ks * 32);
        *reinterpret_cast<f32x4*>(&f[4]) = *reinterpret_cast<const f32x4*>(p + ks * 32 + 4);
        split8(f, ah[ks], al[ks]);
      }
    } else {
      const float* p = h + (size_t)row * FIN + (chunk & 1) * 64 + lq * 8;
#pragma unroll
      for (int ks = 0; ks < 2; ++ks) {
        float f[8];
        if (ok) {
          *reinterpret_cast<f32x4*>(&f[0]) = *reinterpret_cast<const f32x4*>(p + ks * 32);
          *reinterpret_cast<f32x4*>(&f[4]) = *reinterpret_cast<const f32x4*>(p + ks * 32 + 4);
        } else {
#pragma unroll
          for (int i = 0; i < 8; ++i) f[i] = 0.f;
        }
        split8(f, ah[ks], al[ks]);
      }
    }
#pragma unroll
    for (int c = 0; c < NCT; ++c) {
#pragma unroll
      for (int ks = 0; ks < 2; ++ks) {
        bf16x8 b = *reinterpret_cast<const bf16x8*>(
            wpk + ((size_t)(((chunk * NCT + c) * 2 + ks) * 64 + lane)) * 8);
        acc[c] = __builtin_amdgcn_mfma_f32_16x16x32_bf16(b, ah[ks], acc[c], 0, 0, 0);
        acc[c] = __builtin_amdgcn_mfma_f32_16x16x32_bf16(b, al[ks], acc[c], 0, 0, 0);
      }
    }
  }

  // ---- epilogue: bias (+relu), float4 coalesced stores ----
#pragma unroll
  for (int c = 0; c < NCT; ++c) {
    const f32x4 bb = *reinterpret_cast<const f32x4*>(bias + c * 16 + lq * 4);
    if (ok) {
      f32x4 v = acc[c] + bb;
      if (RELU) {
#pragma unroll
        for (int q = 0; q < 4; ++q) v[q] = fmaxf(v[q], 0.f);
      }
      *reinterpret_cast<f32x4*>(out + (size_t)row * FOUT + c * 16 + lq * 4) = v;
    }
  }
}

// ---------------- launch ----------------

static inline size_t align512(size_t x) { return (x + 511) & ~(size_t)511; }

extern "C" void kernel_launch(void* const* d_in, const int* in_sizes, int n_in,
                              void* d_out, int out_size, void* d_ws, size_t ws_size,
                              hipStream_t stream) {
  const float* x   = (const float*)d_in[0];
  const int*   ei  = (const int*)d_in[1];
  const float* Wl0 = (const float*)d_in[2];
  const float* bl0 = (const float*)d_in[3];
  const float* Wr0 = (const float*)d_in[4];
  const float* Wl1 = (const float*)d_in[5];
  const float* bl1 = (const float*)d_in[6];
  const float* Wr1 = (const float*)d_in[7];
  const float* Wl2 = (const float*)d_in[8];
  const float* bl2 = (const float*)d_in[9];
  const float* Wr2 = (const float*)d_in[10];
  float* out = (float*)d_out;

  char* ws = (char*)d_ws;
  size_t off = 0;
  float* inv    = (float*)(ws + off); off = align512(off + (size_t)NN * 4);
  float* h1     = (float*)(ws + off); off = align512(off + (size_t)NN * FIN * 4);
  float* h2     = (float*)(ws + off); off = align512(off + (size_t)NN * FIN * 4);
  short* wpk0   = (short*)(ws + off); off = align512(off + (size_t)128 * 256 * 2);
  short* wpk1   = (short*)(ws + off); off = align512(off + (size_t)128 * 256 * 2);
  short* wpk2   = (short*)(ws + off); off = align512(off + (size_t)64 * 256 * 2);
  int*   deg    = (int*)(ws + off);   // deg + cursor adjacent: zeroed in one call
  int*   cursor = deg + NN;           off = align512(off + (size_t)2 * NN * 4);
  int*   rowptr = (int*)(ws + off);   off = align512(off + (size_t)(NN + 1) * 4);
  int*   bsum   = (int*)(ws + off);   off = align512(off + (size_t)SCAN_BLOCKS * 4);
  int*   adj    = (int*)(ws + off);   off = align512(off + (size_t)NE * 4);

  const int* srcp = ei;
  const int* dstp = ei + NE;

  const int fused_blocks = (NN + 63) / 64;  // 1563

  // ---- weight pre-cast (independent of graph) ----
  k_castw<128><<<128, 256, 0, stream>>>(Wl0, Wr0, wpk0);
  k_castw<128><<<128, 256, 0, stream>>>(Wl1, Wr1, wpk1);
  k_castw<64><<<64, 256, 0, stream>>>(Wl2, Wr2, wpk2);

  // ---- CSR build (once; graph shared across layers) ----
  k_zero<<<128, 256, 0, stream>>>((float4*)deg, 2 * NN / 4);
  k_count<<<(NE + 255) / 256, 256, 0, stream>>>(dstp, deg);
  k_scan1<<<SCAN_BLOCKS, 256, 0, stream>>>(deg, rowptr, bsum);
  k_scan2<<<1, 512, 0, stream>>>(bsum, SCAN_BLOCKS);
  k_scan3<<<SCAN_BLOCKS, 256, 0, stream>>>(bsum, rowptr);
  k_fill<<<(NE + 255) / 256, 256, 0, stream>>>(srcp, dstp, rowptr, cursor, adj);
  k_invdeg<<<(NN + 255) / 256, 256, 0, stream>>>(deg, inv);

  // ---- 3 fused layers ----
  k_fused<128, true><<<fused_blocks, 256, 0, stream>>>(rowptr, adj, x, inv, wpk0, bl0, h1);
  k_fused<128, true><<<fused_blocks, 256, 0, stream>>>(rowptr, adj, h1, inv, wpk1, bl1, h2);
  k_fused<64, false><<<fused_blocks, 256, 0, stream>>>(rowptr, adj, h2, inv, wpk2, bl2, out);
}

// Round 5
// 315.455 us; speedup vs baseline: 10.9662x; 1.0209x over previous
//
#include <hip/hip_runtime.h>

#define NN 100000
#define NE 600000
constexpr int FIN = 128;
constexpr int SCAN_BLOCKS = (NN + 255) / 256;  // 391

typedef __attribute__((ext_vector_type(8))) short bf16x8;
typedef __attribute__((ext_vector_type(4))) float f32x4;

// ---------------- helpers ----------------
__device__ __forceinline__ unsigned packbf2(float a, float b) {  // RNE both halves
  unsigned ua = __float_as_uint(a); ua += 0x7FFFu + ((ua >> 16) & 1u);
  unsigned ub = __float_as_uint(b); ub += 0x7FFFu + ((ub >> 16) & 1u);
  return (ua >> 16) | (ub & 0xFFFF0000u);
}
__device__ __forceinline__ float lo16f(unsigned u) { return __uint_as_float(u << 16); }
__device__ __forceinline__ float hi16f(unsigned u) { return __uint_as_float(u & 0xFFFF0000u); }

// ---------------- utility kernels ----------------

__global__ __launch_bounds__(256) void k_zero(float4* p, int n4) {
  int i = blockIdx.x * blockDim.x + threadIdx.x;
  int st = gridDim.x * blockDim.x;
  for (; i < n4; i += st) p[i] = make_float4(0.f, 0.f, 0.f, 0.f);
}

// fp32 -> bf16 row-major cast (8 elems/thread)
__global__ __launch_bounds__(256) void k_cast(const float* __restrict__ in,
                                              short* __restrict__ outb, int n8) {
  int i = blockIdx.x * blockDim.x + threadIdx.x;
  if (i >= n8) return;
  const float4 v0 = *reinterpret_cast<const float4*>(in + (size_t)i * 8);
  const float4 v1 = *reinterpret_cast<const float4*>(in + (size_t)i * 8 + 4);
  uint4 o;
  o.x = packbf2(v0.x, v0.y);
  o.y = packbf2(v0.z, v0.w);
  o.z = packbf2(v1.x, v1.y);
  o.w = packbf2(v1.z, v1.w);
  *reinterpret_cast<uint4*>(outb + (size_t)i * 8) = o;
}

__global__ __launch_bounds__(256) void k_count(const int* __restrict__ dst,
                                               int* __restrict__ deg) {
  int e = blockIdx.x * blockDim.x + threadIdx.x;
  if (e < NE) {
    int d = dst[e];
    if ((unsigned)d < NN) atomicAdd(&deg[d], 1);
  }
}

__global__ __launch_bounds__(256) void k_invdeg(const int* __restrict__ deg,
                                                float* __restrict__ inv) {
  int i = blockIdx.x * blockDim.x + threadIdx.x;
  if (i < NN) inv[i] = 1.0f / fmaxf((float)deg[i], 1.0f);
}

// ---------------- CSR build: scan + fill ----------------

__global__ __launch_bounds__(256) void k_scan1(const int* __restrict__ deg,
                                               int* __restrict__ rowptr,
                                               int* __restrict__ bsum) {
  __shared__ int s[256];
  int i = blockIdx.x * 256 + threadIdx.x;
  int v = (i < NN) ? deg[i] : 0;
  s[threadIdx.x] = v;
  __syncthreads();
#pragma unroll
  for (int off = 1; off < 256; off <<= 1) {
    int t = (threadIdx.x >= off) ? s[threadIdx.x - off] : 0;
    __syncthreads();
    s[threadIdx.x] += t;
    __syncthreads();
  }
  if (i < NN) rowptr[i + 1] = s[threadIdx.x];
  if (threadIdx.x == 255) bsum[blockIdx.x] = s[255];
}

__global__ __launch_bounds__(512) void k_scan2(int* __restrict__ bsum, int nb) {
  __shared__ int s[512];
  int v = (threadIdx.x < nb) ? bsum[threadIdx.x] : 0;
  s[threadIdx.x] = v;
  __syncthreads();
#pragma unroll
  for (int off = 1; off < 512; off <<= 1) {
    int t = (threadIdx.x >= off) ? s[threadIdx.x - off] : 0;
    __syncthreads();
    s[threadIdx.x] += t;
    __syncthreads();
  }
  if (threadIdx.x < nb) bsum[threadIdx.x] = s[threadIdx.x];
}

__global__ __launch_bounds__(256) void k_scan3(const int* __restrict__ bsum,
                                               int* __restrict__ rowptr) {
  int i = blockIdx.x * 256 + threadIdx.x;
  if (i < NN && blockIdx.x > 0) rowptr[i + 1] += bsum[blockIdx.x - 1];
  if (i == 0) rowptr[0] = 0;
}

__global__ __launch_bounds__(256) void k_fill(const int* __restrict__ src,
                                              const int* __restrict__ dst,
                                              const int* __restrict__ rowptr,
                                              int* __restrict__ cursor,
                                              int* __restrict__ adj) {
  int e = blockIdx.x * blockDim.x + threadIdx.x;
  if (e < NE) {
    int d = dst[e];
    int s = src[e];
    if ((unsigned)d < NN && (unsigned)s < NN) {
      int pos = atomicAdd(&cursor[d], 1);
      adj[rowptr[d] + pos] = s;
    }
  }
}

// ---------------- weight pre-cast into per-lane packed fragment order ----
template <int FOUT>
__global__ __launch_bounds__(256) void k_castw(const float* __restrict__ Wl,
                                               const float* __restrict__ Wr,
                                               short* __restrict__ wpk) {
  constexpr int NCT = FOUT / 16;
  int pidx = blockIdx.x * 256 + threadIdx.x;
  if (pidx >= FOUT * 256) return;
  int t = pidx & 7;
  int lane = (pidx >> 3) & 63;
  int ks = (pidx >> 9) & 1;
  int c = (pidx >> 10) & (NCT - 1);
  int chunk = pidx >> (10 + (NCT == 8 ? 3 : 2));
  int l15 = lane & 15, lq = lane >> 4;
  int j = c * 16 + l15;
  int k = chunk * 64 + ks * 32 + lq * 8 + t;
  float v = (k < 128) ? Wl[j * 128 + k] : Wr[j * 128 + (k - 128)];
  unsigned u = __float_as_uint(v);
  u += 0x7FFFu + ((u >> 16) & 1u);
  wpk[pidx] = (short)(u >> 16);
}

// ---------------- fused gather(bf16) + MFMA GEMM ----------------
__device__ __forceinline__ void split8(const float* f, bf16x8& hi, bf16x8& lo) {
#pragma unroll
  for (int i = 0; i < 8; ++i) {
    unsigned u = __float_as_uint(f[i]);
    hi[i] = (short)(u >> 16);  // truncate; lo catches residual
    float r = f[i] - __uint_as_float(u & 0xFFFF0000u);
    lo[i] = (short)(__float_as_uint(r) >> 16);
  }
}

template <int FOUT, bool RELU, bool WHB>
__global__ __launch_bounds__(256, 4) void k_fused(
    const int* __restrict__ rowptr, const int* __restrict__ adj,
    const float* __restrict__ h, const short* __restrict__ hb,
    const float* __restrict__ inv, const short* __restrict__ wpk,
    const float* __restrict__ bias, float* __restrict__ out,
    short* __restrict__ outb) {
  constexpr int NCT = FOUT / 16;
  constexpr int LSTR = 132;  // +4 pad: A-frag reads 2-way on banks (free)
  __shared__ float lds[4][16 * LSTR];
  const int lane = threadIdx.x & 63;
  const int w = threadIdx.x >> 6;
  const int l15 = lane & 15;
  const int lq = lane >> 4;
  const int half = lane >> 5;
  const int l31 = lane & 31;
  const int n0 = blockIdx.x * 64 + w * 16;
  float* myLds = lds[w];

  // ---- phase 1: gather from bf16 rows (4-deep unroll for MLP) ----
  // half-wave per node; lane covers 4 bf16 (8 B) of the 128-wide row
  for (int i = 0; i < 8; ++i) {
    int node = n0 + 2 * i + half;
    float a0 = 0.f, a1 = 0.f, a2 = 0.f, a3 = 0.f;
    float s = 0.f;
    if (node < NN) {
      int beg = rowptr[node];
      int end = rowptr[node + 1];
      s = inv[node];
      int e = beg;
      for (; e + 3 < end; e += 4) {
        int s0 = adj[e], s1 = adj[e + 1], s2 = adj[e + 2], s3 = adj[e + 3];
        uint2 v0 = *reinterpret_cast<const uint2*>(hb + (size_t)s0 * FIN + l31 * 4);
        uint2 v1 = *reinterpret_cast<const uint2*>(hb + (size_t)s1 * FIN + l31 * 4);
        uint2 v2 = *reinterpret_cast<const uint2*>(hb + (size_t)s2 * FIN + l31 * 4);
        uint2 v3 = *reinterpret_cast<const uint2*>(hb + (size_t)s3 * FIN + l31 * 4);
        a0 += lo16f(v0.x) + lo16f(v1.x) + lo16f(v2.x) + lo16f(v3.x);
        a1 += hi16f(v0.x) + hi16f(v1.x) + hi16f(v2.x) + hi16f(v3.x);
        a2 += lo16f(v0.y) + lo16f(v1.y) + lo16f(v2.y) + lo16f(v3.y);
        a3 += hi16f(v0.y) + hi16f(v1.y) + hi16f(v2.y) + hi16f(v3.y);
      }
      for (; e < end; ++e) {
        int s0 = adj[e];
        uint2 v0 = *reinterpret_cast<const uint2*>(hb + (size_t)s0 * FIN + l31 * 4);
        a0 += lo16f(v0.x);
        a1 += hi16f(v0.x);
        a2 += lo16f(v0.y);
        a3 += hi16f(v0.y);
      }
    }
    float4 m = make_float4(a0 * s, a1 * s, a2 * s, a3 * s);
    *reinterpret_cast<float4*>(&myLds[(2 * i + half) * LSTR + l31 * 4]) = m;
  }

  // ---- phase 2: MFMA over 4 K-chunks of 64 ----
  f32x4 acc[NCT];
#pragma unroll
  for (int c = 0; c < NCT; ++c)
#pragma unroll
    for (int q = 0; q < 4; ++q) acc[c][q] = 0.f;

  const int row = n0 + l15;
  const bool ok = (row < NN);

  for (int chunk = 0; chunk < 4; ++chunk) {
    bf16x8 ah[2], al[2];
    if (chunk < 2) {
      const float* p = &myLds[l15 * LSTR + chunk * 64 + lq * 8];
#pragma unroll
      for (int ks = 0; ks < 2; ++ks) {
        float f[8];
        *reinterpret_cast<f32x4*>(&f[0]) = *reinterpret_cast<const f32x4*>(p + ks * 32);
        *reinterpret_cast<f32x4*>(&f[4]) = *reinterpret_cast<const f32x4*>(p + ks * 32 + 4);
        split8(f, ah[ks], al[ks]);
      }
    } else {
      const float* p = h + (size_t)row * FIN + (chunk & 1) * 64 + lq * 8;
#pragma unroll
      for (int ks = 0; ks < 2; ++ks) {
        float f[8];
        if (ok) {
          *reinterpret_cast<f32x4*>(&f[0]) = *reinterpret_cast<const f32x4*>(p + ks * 32);
          *reinterpret_cast<f32x4*>(&f[4]) = *reinterpret_cast<const f32x4*>(p + ks * 32 + 4);
        } else {
#pragma unroll
          for (int i = 0; i < 8; ++i) f[i] = 0.f;
        }
        split8(f, ah[ks], al[ks]);
      }
    }
#pragma unroll
    for (int c = 0; c < NCT; ++c) {
#pragma unroll
      for (int ks = 0; ks < 2; ++ks) {
        bf16x8 b = *reinterpret_cast<const bf16x8*>(
            wpk + ((size_t)(((chunk * NCT + c) * 2 + ks) * 64 + lane)) * 8);
        acc[c] = __builtin_amdgcn_mfma_f32_16x16x32_bf16(b, ah[ks], acc[c], 0, 0, 0);
        acc[c] = __builtin_amdgcn_mfma_f32_16x16x32_bf16(b, al[ks], acc[c], 0, 0, 0);
      }
    }
  }

  // ---- epilogue: bias (+relu), fp32 stores + optional bf16 shadow ----
#pragma unroll
  for (int c = 0; c < NCT; ++c) {
    const f32x4 bb = *reinterpret_cast<const f32x4*>(bias + c * 16 + lq * 4);
    if (ok) {
      f32x4 v = acc[c] + bb;
      if (RELU) {
#pragma unroll
        for (int q = 0; q < 4; ++q) v[q] = fmaxf(v[q], 0.f);
      }
      *reinterpret_cast<f32x4*>(out + (size_t)row * FOUT + c * 16 + lq * 4) = v;
      if (WHB) {
        uint2 o;
        o.x = packbf2(v[0], v[1]);
        o.y = packbf2(v[2], v[3]);
        *reinterpret_cast<uint2*>(outb + (size_t)row * FOUT + c * 16 + lq * 4) = o;
      }
    }
  }
}

// ---------------- launch ----------------

static inline size_t align512(size_t x) { return (x + 511) & ~(size_t)511; }

extern "C" void kernel_launch(void* const* d_in, const int* in_sizes, int n_in,
                              void* d_out, int out_size, void* d_ws, size_t ws_size,
                              hipStream_t stream) {
  const float* x   = (const float*)d_in[0];
  const int*   ei  = (const int*)d_in[1];
  const float* Wl0 = (const float*)d_in[2];
  const float* bl0 = (const float*)d_in[3];
  const float* Wr0 = (const float*)d_in[4];
  const float* Wl1 = (const float*)d_in[5];
  const float* bl1 = (const float*)d_in[6];
  const float* Wr1 = (const float*)d_in[7];
  const float* Wl2 = (const float*)d_in[8];
  const float* bl2 = (const float*)d_in[9];
  const float* Wr2 = (const float*)d_in[10];
  float* out = (float*)d_out;

  char* ws = (char*)d_ws;
  size_t off = 0;
  float* inv    = (float*)(ws + off); off = align512(off + (size_t)NN * 4);
  float* h1     = (float*)(ws + off); off = align512(off + (size_t)NN * FIN * 4);
  float* h2     = (float*)(ws + off); off = align512(off + (size_t)NN * FIN * 4);
  short* xb     = (short*)(ws + off); off = align512(off + (size_t)NN * FIN * 2);
  short* hb1    = (short*)(ws + off); off = align512(off + (size_t)NN * FIN * 2);
  short* hb2    = (short*)(ws + off); off = align512(off + (size_t)NN * FIN * 2);
  short* wpk0   = (short*)(ws + off); off = align512(off + (size_t)128 * 256 * 2);
  short* wpk1   = (short*)(ws + off); off = align512(off + (size_t)128 * 256 * 2);
  short* wpk2   = (short*)(ws + off); off = align512(off + (size_t)64 * 256 * 2);
  int*   deg    = (int*)(ws + off);   // deg + cursor adjacent: zeroed in one call
  int*   cursor = deg + NN;           off = align512(off + (size_t)2 * NN * 4);
  int*   rowptr = (int*)(ws + off);   off = align512(off + (size_t)(NN + 1) * 4);
  int*   bsum   = (int*)(ws + off);   off = align512(off + (size_t)SCAN_BLOCKS * 4);
  int*   adj    = (int*)(ws + off);   off = align512(off + (size_t)NE * 4);

  const int* srcp = ei;
  const int* dstp = ei + NE;

  const int fused_blocks = (NN + 63) / 64;  // 1563
  const int cast_blocks = (NN * FIN / 8 + 255) / 256;  // 6250

  // ---- weight pre-cast + x bf16 shadow (independent of graph) ----
  k_castw<128><<<128, 256, 0, stream>>>(Wl0, Wr0, wpk0);
  k_castw<128><<<128, 256, 0, stream>>>(Wl1, Wr1, wpk1);
  k_castw<64><<<64, 256, 0, stream>>>(Wl2, Wr2, wpk2);
  k_cast<<<cast_blocks, 256, 0, stream>>>(x, xb, NN * FIN / 8);

  // ---- CSR build (once; graph shared across layers) ----
  k_zero<<<128, 256, 0, stream>>>((float4*)deg, 2 * NN / 4);
  k_count<<<(NE + 255) / 256, 256, 0, stream>>>(dstp, deg);
  k_scan1<<<SCAN_BLOCKS, 256, 0, stream>>>(deg, rowptr, bsum);
  k_scan2<<<1, 512, 0, stream>>>(bsum, SCAN_BLOCKS);
  k_scan3<<<SCAN_BLOCKS, 256, 0, stream>>>(bsum, rowptr);
  k_fill<<<(NE + 255) / 256, 256, 0, stream>>>(srcp, dstp, rowptr, cursor, adj);
  k_invdeg<<<(NN + 255) / 256, 256, 0, stream>>>(deg, inv);

  // ---- 3 fused layers ----
  k_fused<128, true, true><<<fused_blocks, 256, 0, stream>>>(
      rowptr, adj, x, xb, inv, wpk0, bl0, h1, hb1);
  k_fused<128, true, true><<<fused_blocks, 256, 0, stream>>>(
      rowptr, adj, h1, hb1, inv, wpk1, bl1, h2, hb2);
  k_fused<64, false, false><<<fused_blocks, 256, 0, stream>>>(
      rowptr, adj, h2, hb2, inv, wpk2, bl2, out, nullptr);
}

// Round 6
// 243.878 us; speedup vs baseline: 14.1848x; 1.2935x over previous
//
#include <hip/hip_runtime.h>

#define NN 100000
#define NE 600000
constexpr int FIN = 128;
constexpr int SCAN_BLOCKS = (NN + 255) / 256;  // 391

typedef __attribute__((ext_vector_type(8))) short bf16x8;
typedef __attribute__((ext_vector_type(4))) float f32x4;

// ---------------- helpers ----------------
__device__ __forceinline__ unsigned packbf2(float a, float b) {  // RNE both halves
  unsigned ua = __float_as_uint(a); ua += 0x7FFFu + ((ua >> 16) & 1u);
  unsigned ub = __float_as_uint(b); ub += 0x7FFFu + ((ub >> 16) & 1u);
  return (ua >> 16) | (ub & 0xFFFF0000u);
}
__device__ __forceinline__ float lo16f(unsigned u) { return __uint_as_float(u << 16); }
__device__ __forceinline__ float hi16f(unsigned u) { return __uint_as_float(u & 0xFFFF0000u); }

// ---------------- utility kernels ----------------

__global__ __launch_bounds__(256) void k_zero(float4* p, int n4) {
  int i = blockIdx.x * blockDim.x + threadIdx.x;
  int st = gridDim.x * blockDim.x;
  for (; i < n4; i += st) p[i] = make_float4(0.f, 0.f, 0.f, 0.f);
}

// fp32 -> bf16 row-major cast (8 elems/thread)
__global__ __launch_bounds__(256) void k_cast(const float* __restrict__ in,
                                              short* __restrict__ outb, int n8) {
  int i = blockIdx.x * blockDim.x + threadIdx.x;
  if (i >= n8) return;
  const float4 v0 = *reinterpret_cast<const float4*>(in + (size_t)i * 8);
  const float4 v1 = *reinterpret_cast<const float4*>(in + (size_t)i * 8 + 4);
  uint4 o;
  o.x = packbf2(v0.x, v0.y);
  o.y = packbf2(v0.z, v0.w);
  o.z = packbf2(v1.x, v1.y);
  o.w = packbf2(v1.z, v1.w);
  *reinterpret_cast<uint4*>(outb + (size_t)i * 8) = o;
}

__global__ __launch_bounds__(256) void k_count(const int* __restrict__ dst,
                                               int* __restrict__ deg) {
  int e = blockIdx.x * blockDim.x + threadIdx.x;
  if (e < NE) {
    int d = dst[e];
    if ((unsigned)d < NN) atomicAdd(&deg[d], 1);
  }
}

__global__ __launch_bounds__(256) void k_invdeg(const int* __restrict__ deg,
                                                float* __restrict__ inv) {
  int i = blockIdx.x * blockDim.x + threadIdx.x;
  if (i < NN) inv[i] = 1.0f / fmaxf((float)deg[i], 1.0f);
}

// ---------------- CSR build: scan + fill ----------------

__global__ __launch_bounds__(256) void k_scan1(const int* __restrict__ deg,
                                               int* __restrict__ rowptr,
                                               int* __restrict__ bsum) {
  __shared__ int s[256];
  int i = blockIdx.x * 256 + threadIdx.x;
  int v = (i < NN) ? deg[i] : 0;
  s[threadIdx.x] = v;
  __syncthreads();
#pragma unroll
  for (int off = 1; off < 256; off <<= 1) {
    int t = (threadIdx.x >= off) ? s[threadIdx.x - off] : 0;
    __syncthreads();
    s[threadIdx.x] += t;
    __syncthreads();
  }
  if (i < NN) rowptr[i + 1] = s[threadIdx.x];
  if (threadIdx.x == 255) bsum[blockIdx.x] = s[255];
}

__global__ __launch_bounds__(512) void k_scan2(int* __restrict__ bsum, int nb) {
  __shared__ int s[512];
  int v = (threadIdx.x < nb) ? bsum[threadIdx.x] : 0;
  s[threadIdx.x] = v;
  __syncthreads();
#pragma unroll
  for (int off = 1; off < 512; off <<= 1) {
    int t = (threadIdx.x >= off) ? s[threadIdx.x - off] : 0;
    __syncthreads();
    s[threadIdx.x] += t;
    __syncthreads();
  }
  if (threadIdx.x < nb) bsum[threadIdx.x] = s[threadIdx.x];
}

__global__ __launch_bounds__(256) void k_scan3(const int* __restrict__ bsum,
                                               int* __restrict__ rowptr) {
  int i = blockIdx.x * 256 + threadIdx.x;
  if (i < NN && blockIdx.x > 0) rowptr[i + 1] += bsum[blockIdx.x - 1];
  if (i == 0) rowptr[0] = 0;
}

__global__ __launch_bounds__(256) void k_fill(const int* __restrict__ src,
                                              const int* __restrict__ dst,
                                              const int* __restrict__ rowptr,
                                              int* __restrict__ cursor,
                                              int* __restrict__ adj) {
  int e = blockIdx.x * blockDim.x + threadIdx.x;
  if (e < NE) {
    int d = dst[e];
    int s = src[e];
    if ((unsigned)d < NN && (unsigned)s < NN) {
      int pos = atomicAdd(&cursor[d], 1);
      adj[rowptr[d] + pos] = s;
    }
  }
}

// ---------------- weight pre-cast into per-lane packed fragment order ----
// pidx = (((chunk*NCT + c)*2 + ks)*64 + lane)*8 + t
// value = bf16( W[j=c*16+(lane&15)][k=chunk*64+ks*32+(lane>>4)*8+t] ), W=[Wl|Wr]
template <int FOUT>
__global__ __launch_bounds__(256) void k_castw(const float* __restrict__ Wl,
                                               const float* __restrict__ Wr,
                                               short* __restrict__ wpk) {
  constexpr int NCT = FOUT / 16;
  int pidx = blockIdx.x * 256 + threadIdx.x;
  if (pidx >= FOUT * 256) return;
  int t = pidx & 7;
  int lane = (pidx >> 3) & 63;
  int ks = (pidx >> 9) & 1;
  int c = (pidx >> 10) & (NCT - 1);
  int chunk = pidx >> (10 + (NCT == 8 ? 3 : 2));
  int l15 = lane & 15, lq = lane >> 4;
  int j = c * 16 + l15;
  int k = chunk * 64 + ks * 32 + lq * 8 + t;
  float v = (k < 128) ? Wl[j * 128 + k] : Wr[j * 128 + (k - 128)];
  unsigned u = __float_as_uint(v);
  u += 0x7FFFu + ((u >> 16) & 1u);
  wpk[pidx] = (short)(u >> 16);
}

// ---------------- fused gather(bf16) + MFMA GEMM (bf16 activations) ------
// Wave owns 16 rows. Phase 1: quarter-wave (16 lanes) per node, 4 nodes
// concurrent, 4-deep edge unroll; fp32 accumulate; bf16 mean -> wave-private
// LDS. Phase 2: single-bf16 MFMA, K=256 = [mean | h]; bias+relu epilogue.
// No barriers anywhere.
template <int FOUT, bool RELU, bool WF32, bool WB16>
__global__ __launch_bounds__(256, 6) void k_fused(
    const int* __restrict__ rowptr, const int* __restrict__ adj,
    const short* __restrict__ hb, const float* __restrict__ inv,
    const short* __restrict__ wpk, const float* __restrict__ bias,
    float* __restrict__ out, short* __restrict__ outb) {
  constexpr int NCT = FOUT / 16;
  constexpr int LSTR = 136;  // shorts; 272 B rows (16B-aligned, odd 16B units)
  __shared__ short lds[4][16 * LSTR];
  const int lane = threadIdx.x & 63;
  const int w = threadIdx.x >> 6;
  const int l15 = lane & 15;
  const int lq = lane >> 4;      // 0..3 : quarter-wave id (phase 1) / k-octet (phase 2 uses >>4 of 0..63: 0..3)
  const int n0 = blockIdx.x * 64 + w * 16;
  short* myLds = lds[w];

  // ---- phase 1: gather; quarter-wave per node; lane covers 8 bf16 (16 B) ----
  for (int i = 0; i < 4; ++i) {
    const int node = n0 + 4 * i + lq;
    float a0 = 0.f, a1 = 0.f, a2 = 0.f, a3 = 0.f;
    float a4 = 0.f, a5 = 0.f, a6 = 0.f, a7 = 0.f;
    float s = 0.f;
    if (node < NN) {
      const int beg = rowptr[node];
      const int end = rowptr[node + 1];
      s = inv[node];
      int e = beg;
      for (; e + 3 < end; e += 4) {
        int s0 = adj[e], s1 = adj[e + 1], s2 = adj[e + 2], s3 = adj[e + 3];
        uint4 v0 = *reinterpret_cast<const uint4*>(hb + (size_t)s0 * FIN + l15 * 8);
        uint4 v1 = *reinterpret_cast<const uint4*>(hb + (size_t)s1 * FIN + l15 * 8);
        uint4 v2 = *reinterpret_cast<const uint4*>(hb + (size_t)s2 * FIN + l15 * 8);
        uint4 v3 = *reinterpret_cast<const uint4*>(hb + (size_t)s3 * FIN + l15 * 8);
        a0 += lo16f(v0.x) + lo16f(v1.x) + lo16f(v2.x) + lo16f(v3.x);
        a1 += hi16f(v0.x) + hi16f(v1.x) + hi16f(v2.x) + hi16f(v3.x);
        a2 += lo16f(v0.y) + lo16f(v1.y) + lo16f(v2.y) + lo16f(v3.y);
        a3 += hi16f(v0.y) + hi16f(v1.y) + hi16f(v2.y) + hi16f(v3.y);
        a4 += lo16f(v0.z) + lo16f(v1.z) + lo16f(v2.z) + lo16f(v3.z);
        a5 += hi16f(v0.z) + hi16f(v1.z) + hi16f(v2.z) + hi16f(v3.z);
        a6 += lo16f(v0.w) + lo16f(v1.w) + lo16f(v2.w) + lo16f(v3.w);
        a7 += hi16f(v0.w) + hi16f(v1.w) + hi16f(v2.w) + hi16f(v3.w);
      }
      for (; e < end; ++e) {
        int s0 = adj[e];
        uint4 v0 = *reinterpret_cast<const uint4*>(hb + (size_t)s0 * FIN + l15 * 8);
        a0 += lo16f(v0.x); a1 += hi16f(v0.x);
        a2 += lo16f(v0.y); a3 += hi16f(v0.y);
        a4 += lo16f(v0.z); a5 += hi16f(v0.z);
        a6 += lo16f(v0.w); a7 += hi16f(v0.w);
      }
    }
    uint4 o;
    o.x = packbf2(a0 * s, a1 * s);
    o.y = packbf2(a2 * s, a3 * s);
    o.z = packbf2(a4 * s, a5 * s);
    o.w = packbf2(a6 * s, a7 * s);
    *reinterpret_cast<uint4*>(&myLds[(4 * i + lq) * LSTR + l15 * 8]) = o;
  }

  // ---- phase 2: MFMA over 4 K-chunks of 64 (single bf16 A) ----
  f32x4 acc[NCT];
#pragma unroll
  for (int c = 0; c < NCT; ++c)
#pragma unroll
    for (int q = 0; q < 4; ++q) acc[c][q] = 0.f;

  const int row = n0 + l15;
  const bool ok = (row < NN);

  for (int chunk = 0; chunk < 4; ++chunk) {
    bf16x8 a[2];
    if (chunk < 2) {
#pragma unroll
      for (int ks = 0; ks < 2; ++ks)
        a[ks] = *reinterpret_cast<const bf16x8*>(
            &myLds[l15 * LSTR + chunk * 64 + ks * 32 + lq * 8]);
    } else {
      const short* p = hb + (size_t)row * FIN + (chunk & 1) * 64 + lq * 8;
#pragma unroll
      for (int ks = 0; ks < 2; ++ks) {
        if (ok) {
          a[ks] = *reinterpret_cast<const bf16x8*>(p + ks * 32);
        } else {
#pragma unroll
          for (int i = 0; i < 8; ++i) a[ks][i] = 0;
        }
      }
    }
#pragma unroll
    for (int c = 0; c < NCT; ++c) {
#pragma unroll
      for (int ks = 0; ks < 2; ++ks) {
        bf16x8 b = *reinterpret_cast<const bf16x8*>(
            wpk + ((size_t)(((chunk * NCT + c) * 2 + ks) * 64 + lane)) * 8);
        acc[c] = __builtin_amdgcn_mfma_f32_16x16x32_bf16(b, a[ks], acc[c], 0, 0, 0);
      }
    }
  }

  // ---- epilogue: bias (+relu); bf16 shadow and/or fp32 stores ----
#pragma unroll
  for (int c = 0; c < NCT; ++c) {
    const f32x4 bb = *reinterpret_cast<const f32x4*>(bias + c * 16 + lq * 4);
    if (ok) {
      f32x4 v = acc[c] + bb;
      if (RELU) {
#pragma unroll
        for (int q = 0; q < 4; ++q) v[q] = fmaxf(v[q], 0.f);
      }
      if (WF32)
        *reinterpret_cast<f32x4*>(out + (size_t)row * FOUT + c * 16 + lq * 4) = v;
      if (WB16) {
        uint2 o;
        o.x = packbf2(v[0], v[1]);
        o.y = packbf2(v[2], v[3]);
        *reinterpret_cast<uint2*>(outb + (size_t)row * FOUT + c * 16 + lq * 4) = o;
      }
    }
  }
}

// ---------------- launch ----------------

static inline size_t align512(size_t x) { return (x + 511) & ~(size_t)511; }

extern "C" void kernel_launch(void* const* d_in, const int* in_sizes, int n_in,
                              void* d_out, int out_size, void* d_ws, size_t ws_size,
                              hipStream_t stream) {
  const float* x   = (const float*)d_in[0];
  const int*   ei  = (const int*)d_in[1];
  const float* Wl0 = (const float*)d_in[2];
  const float* bl0 = (const float*)d_in[3];
  const float* Wr0 = (const float*)d_in[4];
  const float* Wl1 = (const float*)d_in[5];
  const float* bl1 = (const float*)d_in[6];
  const float* Wr1 = (const float*)d_in[7];
  const float* Wl2 = (const float*)d_in[8];
  const float* bl2 = (const float*)d_in[9];
  const float* Wr2 = (const float*)d_in[10];
  float* out = (float*)d_out;

  char* ws = (char*)d_ws;
  size_t off = 0;
  float* inv    = (float*)(ws + off); off = align512(off + (size_t)NN * 4);
  short* xb     = (short*)(ws + off); off = align512(off + (size_t)NN * FIN * 2);
  short* hb1    = (short*)(ws + off); off = align512(off + (size_t)NN * FIN * 2);
  short* hb2    = (short*)(ws + off); off = align512(off + (size_t)NN * FIN * 2);
  short* wpk0   = (short*)(ws + off); off = align512(off + (size_t)128 * 256 * 2);
  short* wpk1   = (short*)(ws + off); off = align512(off + (size_t)128 * 256 * 2);
  short* wpk2   = (short*)(ws + off); off = align512(off + (size_t)64 * 256 * 2);
  int*   deg    = (int*)(ws + off);   // deg + cursor adjacent: zeroed in one call
  int*   cursor = deg + NN;           off = align512(off + (size_t)2 * NN * 4);
  int*   rowptr = (int*)(ws + off);   off = align512(off + (size_t)(NN + 1) * 4);
  int*   bsum   = (int*)(ws + off);   off = align512(off + (size_t)SCAN_BLOCKS * 4);
  int*   adj    = (int*)(ws + off);   off = align512(off + (size_t)NE * 4);

  const int* srcp = ei;
  const int* dstp = ei + NE;

  const int fused_blocks = (NN + 63) / 64;             // 1563
  const int cast_blocks = (NN * FIN / 8 + 255) / 256;  // 6250

  // ---- weight pre-cast + x bf16 shadow (independent of graph) ----
  k_castw<128><<<128, 256, 0, stream>>>(Wl0, Wr0, wpk0);
  k_castw<128><<<128, 256, 0, stream>>>(Wl1, Wr1, wpk1);
  k_castw<64><<<64, 256, 0, stream>>>(Wl2, Wr2, wpk2);
  k_cast<<<cast_blocks, 256, 0, stream>>>(x, xb, NN * FIN / 8);

  // ---- CSR build (once; graph shared across layers) ----
  k_zero<<<128, 256, 0, stream>>>((float4*)deg, 2 * NN / 4);
  k_count<<<(NE + 255) / 256, 256, 0, stream>>>(dstp, deg);
  k_scan1<<<SCAN_BLOCKS, 256, 0, stream>>>(deg, rowptr, bsum);
  k_scan2<<<1, 512, 0, stream>>>(bsum, SCAN_BLOCKS);
  k_scan3<<<SCAN_BLOCKS, 256, 0, stream>>>(bsum, rowptr);
  k_fill<<<(NE + 255) / 256, 256, 0, stream>>>(srcp, dstp, rowptr, cursor, adj);
  k_invdeg<<<(NN + 255) / 256, 256, 0, stream>>>(deg, inv);

  // ---- 3 fused layers (bf16 activations end-to-end) ----
  k_fused<128, true, false, true><<<fused_blocks, 256, 0, stream>>>(
      rowptr, adj, xb, inv, wpk0, bl0, nullptr, hb1);
  k_fused<128, true, false, true><<<fused_blocks, 256, 0, stream>>>(
      rowptr, adj, hb1, inv, wpk1, bl1, nullptr, hb2);
  k_fused<64, false, true, false><<<fused_blocks, 256, 0, stream>>>(
      rowptr, adj, hb2, inv, wpk2, bl2, out, nullptr);
}